// Round 12
// baseline (320.960 us; speedup 1.0000x reference)
//
#include <hip/hip_runtime.h>
#include <hip/hip_bf16.h>
#include <cmath>

// Problem constants
#define B_DIM 4
#define T_DIM 2048
#define D_DIM 1024
#define M_DIM 8192          // B*T
#define KP    2048          // physical K for GEMM1 activations: [hi|lo]

#define NCH   64            // scan chunks
#define CHL   32            // T / NCH

using bf16 = __hip_bfloat16;
typedef __attribute__((ext_vector_type(8))) short frag8;   // 8 bf16 (4 VGPRs)
typedef __attribute__((ext_vector_type(4))) float f32x4;   // MFMA accumulator

// ---------------- workspace layout (bytes) ----------------
#define XS_OFF   0L
#define WIN_OFF  33554432L
#define WSS_OFF  37748736L
#define WOS_OFF  39845888L
#define GATE_OFF 41943040L
#define VS_OFF   75497472L
#define AF_OFF   92274688L
#define BF_OFF   125829120L
#define ACH_OFF  159383552L
#define BCH_OFF  160432128L

// ---------------- hi/lo split convert for GEMM1 activations (4 f32/thread) ----------------
__global__ void split_kernel(const float* __restrict__ src, bf16* __restrict__ dst, long total4) {
    long i4 = (long)blockIdx.x * blockDim.x + threadIdx.x;
    if (i4 >= total4) return;
    long i = i4 * 4;
    const float4 v = *(const float4*)&src[i];
    long r = i >> 10;
    int  c = (int)(i & 1023);
    ushort hi[4], lo[4];
    const float vv[4] = {v.x, v.y, v.z, v.w};
#pragma unroll
    for (int j = 0; j < 4; ++j) {
        bf16 h = __float2bfloat16(vv[j]);
        hi[j] = *(ushort*)&h;
        bf16 l2 = __float2bfloat16(vv[j] - __bfloat162float(h));
        lo[j] = *(ushort*)&l2;
    }
    *(ushort4*)&dst[r * KP + c]        = make_ushort4(hi[0], hi[1], hi[2], hi[3]);
    *(ushort4*)&dst[r * KP + c + 1024] = make_ushort4(lo[0], lo[1], lo[2], lo[3]);
}

// merged weight converts: Win(2M) | Wsm(1M) | Wo(1M) f32 -> bf16, one dispatch.
__global__ void wconv_kernel(const float* __restrict__ Win, const float* __restrict__ Wsm,
                             const float* __restrict__ Wo,
                             bf16* __restrict__ Wins, bf16* __restrict__ Wss,
                             bf16* __restrict__ Wos) {
    long i4 = (long)blockIdx.x * 256 + threadIdx.x;   // 0..1048575
    const float* src; bf16* dst; long off;
    if (i4 < 524288)      { src = Win; dst = Wins; off = i4; }
    else if (i4 < 786432) { src = Wsm; dst = Wss;  off = i4 - 524288; }
    else                  { src = Wo;  dst = Wos;  off = i4 - 786432; }
    long i = off * 4;
    const float4 v = *(const float4*)&src[i];
    bf16 h0 = __float2bfloat16(v.x), h1 = __float2bfloat16(v.y);
    bf16 h2 = __float2bfloat16(v.z), h3 = __float2bfloat16(v.w);
    *(ushort4*)&dst[i] = make_ushort4(*(ushort*)&h0, *(ushort*)&h1, *(ushort*)&h2, *(ushort*)&h3);
}

// ---------------- 128x128 / BK=32 / 4-wave / ring-4 GEMM + register frag dbuf ----------------
// C[m,n] = sum_{kt<NTT} A[m, kt*32+..] * Bhi[n, (kt&31)*32+..]
//   GEMM1: NTT=64, LDA=2048 -> (hi_a + lo_a) . hi_b over K'=2048
//   GEMM2/3: NTT=32, LDA=1024 -> plain bf16 K'=1024
// LDS ring-4 (R8-proven 2 blocks/CU, 64 KiB). vs R8: vmcnt cadence shifted one
// tile earlier -> at tile-kt entry tiles kt AND kt+1 are landed, so tile kt+1's
// fragments are ds_read DURING tile kt's MFMA (register X/Y double-buffer, named
// scalars per rule #20). MFMA consumes only registers -> LDS latency off the
// critical path. Steady ladder: {stage; vmcnt(4); barrier} per half-iter keeps
// one tile always in flight; tiles staged 3 ahead of read (> HBM latency).
// Slot audit: pre-read slot (kt+1)&3, stage slots (kt+3)&3 / kt&3 distinct per
// half; staged slot's previous readers' lgkm drained before the preceding barrier.
#define AS1 const __attribute__((address_space(1))) void*
#define AS3 __attribute__((address_space(3))) void*

template<int EPI, int NTT, int LDA>
__global__ __launch_bounds__(256, 2)
void gemm128(const bf16* __restrict__ A, const bf16* __restrict__ Bw,
             const float* __restrict__ bias,
             const float* __restrict__ gatef_in,
             const float* __restrict__ x_in,
             float* __restrict__ out0, float* __restrict__ out1,
             bf16* __restrict__ outv)
{
    __shared__ bf16 As[4][4096];   // [slot][128*32]
    __shared__ bf16 Bs[4][4096];
    const int t  = threadIdx.x;
    const int l  = t & 63;
    const int w  = t >> 6;
    const int wr = w >> 1, wc = w & 1;
    const int bm = blockIdx.x;
    const int bn = blockIdx.y;

    f32x4 acc[4][4] = {};

    // staging: thread t -> rows sr, sr+64; col chunk (t&3), source col pre-swizzled
    const int sr  = t >> 2;                           // 0..63
    const int sg  = (sr & 3) ^ ((sr >> 2) & 3);       // same for sr+64
    const int scS = ((t & 3) * 8) ^ (sg << 3);
    const bf16* Ab = A  + ((long)bm * 128 + sr) * LDA  + scS;
    const bf16* Bb = Bw + ((long)bn * 128 + sr) * 1024 + scS;

    // reader: swizzled k-chunk; g(row) = (l&3)^((l>>2)&3) for all frag rows
    const int rk    = (((l >> 4) ^ (l & 3) ^ ((l >> 2) & 3)) << 3);
    const int rowA0 = wr * 64 + (l & 15);
    const int rowB0 = wc * 64 + (l & 15);

#define STAGE(slot, kt) {                                                          \
    const long ka = (long)(kt) * 32;                                               \
    const long kb = (long)((kt) & 31) * 32;                                        \
    __builtin_amdgcn_global_load_lds((AS1)(Ab + ka),             (AS3)&As[slot][t * 8],        16, 0, 0); \
    __builtin_amdgcn_global_load_lds((AS1)(Ab + 64 * LDA + ka),  (AS3)&As[slot][2048 + t * 8], 16, 0, 0); \
    __builtin_amdgcn_global_load_lds((AS1)(Bb + kb),             (AS3)&Bs[slot][t * 8],        16, 0, 0); \
    __builtin_amdgcn_global_load_lds((AS1)(Bb + 64 * 1024 + kb), (AS3)&Bs[slot][2048 + t * 8], 16, 0, 0); \
}

#define READAB(a0,a1,a2,a3,b0,b1,b2,b3, s) {                                       \
    b0 = *(const frag8*)&Bs[s][(rowB0     ) * 32 + rk];                            \
    b1 = *(const frag8*)&Bs[s][(rowB0 + 16) * 32 + rk];                            \
    b2 = *(const frag8*)&Bs[s][(rowB0 + 32) * 32 + rk];                            \
    b3 = *(const frag8*)&Bs[s][(rowB0 + 48) * 32 + rk];                            \
    a0 = *(const frag8*)&As[s][(rowA0     ) * 32 + rk];                            \
    a1 = *(const frag8*)&As[s][(rowA0 + 16) * 32 + rk];                            \
    a2 = *(const frag8*)&As[s][(rowA0 + 32) * 32 + rk];                            \
    a3 = *(const frag8*)&As[s][(rowA0 + 48) * 32 + rk];                            \
}

#define MFMA16(a0,a1,a2,a3,b0,b1,b2,b3) {                                          \
    acc[0][0] = __builtin_amdgcn_mfma_f32_16x16x32_bf16(a0, b0, acc[0][0], 0, 0, 0); \
    acc[0][1] = __builtin_amdgcn_mfma_f32_16x16x32_bf16(a0, b1, acc[0][1], 0, 0, 0); \
    acc[0][2] = __builtin_amdgcn_mfma_f32_16x16x32_bf16(a0, b2, acc[0][2], 0, 0, 0); \
    acc[0][3] = __builtin_amdgcn_mfma_f32_16x16x32_bf16(a0, b3, acc[0][3], 0, 0, 0); \
    acc[1][0] = __builtin_amdgcn_mfma_f32_16x16x32_bf16(a1, b0, acc[1][0], 0, 0, 0); \
    acc[1][1] = __builtin_amdgcn_mfma_f32_16x16x32_bf16(a1, b1, acc[1][1], 0, 0, 0); \
    acc[1][2] = __builtin_amdgcn_mfma_f32_16x16x32_bf16(a1, b2, acc[1][2], 0, 0, 0); \
    acc[1][3] = __builtin_amdgcn_mfma_f32_16x16x32_bf16(a1, b3, acc[1][3], 0, 0, 0); \
    acc[2][0] = __builtin_amdgcn_mfma_f32_16x16x32_bf16(a2, b0, acc[2][0], 0, 0, 0); \
    acc[2][1] = __builtin_amdgcn_mfma_f32_16x16x32_bf16(a2, b1, acc[2][1], 0, 0, 0); \
    acc[2][2] = __builtin_amdgcn_mfma_f32_16x16x32_bf16(a2, b2, acc[2][2], 0, 0, 0); \
    acc[2][3] = __builtin_amdgcn_mfma_f32_16x16x32_bf16(a2, b3, acc[2][3], 0, 0, 0); \
    acc[3][0] = __builtin_amdgcn_mfma_f32_16x16x32_bf16(a3, b0, acc[3][0], 0, 0, 0); \
    acc[3][1] = __builtin_amdgcn_mfma_f32_16x16x32_bf16(a3, b1, acc[3][1], 0, 0, 0); \
    acc[3][2] = __builtin_amdgcn_mfma_f32_16x16x32_bf16(a3, b2, acc[3][2], 0, 0, 0); \
    acc[3][3] = __builtin_amdgcn_mfma_f32_16x16x32_bf16(a3, b3, acc[3][3], 0, 0, 0); \
}

    // prologue: tiles 0,1,2 in flight; tiles 0,1 landed before loop
    STAGE(0, 0); STAGE(1, 1); STAGE(2, 2);
    asm volatile("s_waitcnt vmcnt(4)" ::: "memory");   // tiles 0,1 landed (this wave)
    __builtin_amdgcn_s_barrier();                      // ...landed for ALL waves
    asm volatile("" ::: "memory");

    frag8 xa0, xa1, xa2, xa3, xb0, xb1, xb2, xb3;      // tile kt   (even)
    frag8 ya0, ya1, ya2, ya3, yb0, yb1, yb2, yb3;      // tile kt+1 (odd)
    READAB(xa0, xa1, xa2, xa3, xb0, xb1, xb2, xb3, 0); // pre-read tile 0

#pragma unroll 1
    for (int kt = 0; kt < NTT; kt += 2) {
        // ===== even tile kt: MFMA(X) while reading tile kt+1 into Y =====
        if (kt + 3 < NTT) STAGE((kt + 3) & 3, kt + 3);
        READAB(ya0, ya1, ya2, ya3, yb0, yb1, yb2, yb3, (kt + 1) & 3);
        __builtin_amdgcn_s_setprio(1);
        MFMA16(xa0, xa1, xa2, xa3, xb0, xb1, xb2, xb3);
        __builtin_amdgcn_s_setprio(0);
        asm volatile("" ::: "memory");
        if (kt + 3 < NTT) {                            // steady: tile kt+2 landed
            asm volatile("s_waitcnt vmcnt(4)" ::: "memory");
            __builtin_amdgcn_s_barrier();
            asm volatile("" ::: "memory");
        }
        // ===== odd tile kt+1: MFMA(Y) while reading tile kt+2 into X =====
        if (kt + 4 < NTT) STAGE(kt & 3, kt + 4);
        if (kt + 2 < NTT) READAB(xa0, xa1, xa2, xa3, xb0, xb1, xb2, xb3, (kt + 2) & 3);
        __builtin_amdgcn_s_setprio(1);
        MFMA16(ya0, ya1, ya2, ya3, yb0, yb1, yb2, yb3);
        __builtin_amdgcn_s_setprio(0);
        asm volatile("" ::: "memory");
        if (kt + 4 < NTT) {                            // steady: tile kt+3 landed
            asm volatile("s_waitcnt vmcnt(4)" ::: "memory");
            __builtin_amdgcn_s_barrier();
            asm volatile("" ::: "memory");
        } else if (kt + 2 < NTT) {                     // kt==NTT-4: drain tile NTT-1
            asm volatile("s_waitcnt vmcnt(0)" ::: "memory");
            __builtin_amdgcn_s_barrier();
            asm volatile("" ::: "memory");
        }
    }
#undef STAGE
#undef READAB
#undef MFMA16

    // epilogue: C/D layout col=lane&15, row=(lane>>4)*4+j  [m89-verified]
    const int r4 = (l >> 4) * 4;
    const int cl = l & 15;
#pragma unroll
    for (int fm = 0; fm < 4; ++fm) {
#pragma unroll
        for (int fn = 0; fn < 4; ++fn) {
            const int n = bn * 128 + wc * 64 + fn * 16 + cl;
            const float bn_bias = bias[n];
#pragma unroll
            for (int j = 0; j < 4; ++j) {
                const int m = bm * 128 + wr * 64 + fm * 16 + r4 + j;
                float v = acc[fm][fn][j] + bn_bias;
                if (EPI == 1) {
                    if (n < 1024) {
                        out0[(long)m * 1024 + n] = 1.0f / (1.0f + expf(-v));
                    } else {
                        outv[(long)m * 1024 + (n - 1024)] = __float2bfloat16(v);
                    }
                } else if (EPI == 2) {
                    const float sv = tanhf(v);
                    const float g  = gatef_in[(long)m * 1024 + n];
                    out0[(long)m * 1024 + n] = 1.0f - g;
                    out1[(long)m * 1024 + n] = g * sv;
                } else {
                    out0[(long)m * 1024 + n] = x_in[(long)m * 1024 + n] + v;
                }
            }
        }
    }
}

// ---------------- chunked parallel scan: h[t] = a[t]*h[t-1] + b[t] ----------------
__global__ void scan_phase1(const float* __restrict__ af, const float* __restrict__ bfv,
                            float* __restrict__ Ach, float* __restrict__ Bch) {
    int tid = blockIdx.x * 256 + threadIdx.x;   // [chunk][b][d]
    int c = tid >> 12;
    int r = tid & 4095;
    int bi = r >> 10;
    long base = ((long)bi * T_DIM + c * CHL) * D_DIM + (r & 1023);
    float A = 1.0f, Bc = 0.0f;
#pragma unroll 4
    for (int i = 0; i < CHL; ++i) {
        float a = af[base + (long)i * D_DIM];
        float b = bfv[base + (long)i * D_DIM];
        A *= a;
        Bc = a * Bc + b;
    }
    Ach[tid] = A;
    Bch[tid] = Bc;
}

// phase2 fused into phase3: per-thread serial carry over chunk aggregates
__global__ void scan_phase23(const float* __restrict__ af, const float* __restrict__ bfv,
                             const float* __restrict__ Ach, const float* __restrict__ Bch,
                             bf16* __restrict__ Hs) {
    int tid = blockIdx.x * 256 + threadIdx.x;
    int c = tid >> 12;
    int r = tid & 4095;
    int bi = r >> 10;
    int d  = r & 1023;
    float h = 0.0f;
    for (int j = 0; j < c; ++j)
        h = Ach[j * 4096 + r] * h + Bch[j * 4096 + r];
    long base = ((long)bi * T_DIM + c * CHL) * D_DIM + d;
#pragma unroll 4
    for (int i = 0; i < CHL; ++i) {
        float a = af[base + (long)i * D_DIM];
        float b = bfv[base + (long)i * D_DIM];
        h = a * h + b;
        long m = (long)bi * T_DIM + c * CHL + i;
        Hs[m * 1024 + d] = __float2bfloat16(h);
    }
}

// ---------------- launch ----------------
extern "C" void kernel_launch(void* const* d_in, const int* in_sizes, int n_in,
                              void* d_out, int out_size, void* d_ws, size_t ws_size,
                              hipStream_t stream) {
    const float* x   = (const float*)d_in[0];
    const float* Win = (const float*)d_in[1];
    const float* bin = (const float*)d_in[2];
    const float* Wsm = (const float*)d_in[3];
    const float* bs  = (const float*)d_in[4];
    const float* Wo  = (const float*)d_in[5];
    const float* bo  = (const float*)d_in[6];
    float* out = (float*)d_out;
    char*  ws  = (char*)d_ws;

    bf16*  Xs    = (bf16*)(ws + XS_OFF);   // [M][2048] hi|lo; first 16MB reused as Hs
    bf16*  Wins  = (bf16*)(ws + WIN_OFF);
    bf16*  Wss   = (bf16*)(ws + WSS_OFF);
    bf16*  Wos   = (bf16*)(ws + WOS_OFF);
    float* gatef = (float*)(ws + GATE_OFF);
    bf16*  Vs    = (bf16*)(ws + VS_OFF);   // [M][1024] hi only
    float* af    = (float*)(ws + AF_OFF);
    float* bfv   = (float*)(ws + BF_OFF);
    float* Ach   = (float*)(ws + ACH_OFF);
    float* Bch   = (float*)(ws + BCH_OFF);
    bf16*  Hs    = (bf16*)(ws + XS_OFF);   // [M][1024] (aliases Xs)

    // activation split (hi|lo); merged weight converts (1 dispatch)
    split_kernel<<<(M_DIM * D_DIM / 4 + 255) / 256, 256, 0, stream>>>(x, Xs, (long)M_DIM * D_DIM / 4);
    wconv_kernel<<<4096, 256, 0, stream>>>(Win, Wsm, Wo, Wins, Wss, Wos);

    // GEMM1: gv = x @ W_in^T ; gate/val epilogue (K'=2048: hi+lo activations)
    dim3 g1(M_DIM / 128, 2048 / 128);
    gemm128<1, 64, 2048><<<g1, 256, 0, stream>>>(Xs, Wins, bin, nullptr, nullptr, gatef, nullptr, Vs);

    // GEMM2: sv = tanh(val @ W_s^T) ; a,b epilogue (K'=1024: bf16 val)
    dim3 g2(M_DIM / 128, 1024 / 128);
    gemm128<2, 32, 1024><<<g2, 256, 0, stream>>>(Vs, Wss, bs, gatef, nullptr, af, bfv, nullptr);

    // scan: h[t] = a[t]*h[t-1] + b[t]
    scan_phase1 <<<NCH * 4096 / 256, 256, 0, stream>>>(af, bfv, Ach, Bch);
    scan_phase23<<<NCH * 4096 / 256, 256, 0, stream>>>(af, bfv, Ach, Bch, Hs);

    // GEMM3: out = x + h @ W_o^T + b_o (K'=1024: bf16 h)
    gemm128<3, 32, 1024><<<g2, 256, 0, stream>>>(Hs, Wos, bo, nullptr, x, out, nullptr, nullptr);
}